// Round 1
// baseline (1490.016 us; speedup 1.0000x reference)
//
#include <hip/hip_runtime.h>
#include <hip/hip_bf16.h>
#include <math.h>

#define N_NODES 60000
#define E_EDGES 200000
#define DIM     128
#define NINPK   256
#define TSTEPS  6
#define LLAYERS 2
#define BGRAPH  16

static __device__ __forceinline__ float sigm(float x) { return 1.f / (1.f + expf(-x)); }

// order-preserving float <-> uint for atomicMax-based segment max
static __device__ __forceinline__ unsigned fenc(float f) {
  unsigned u = __float_as_uint(f);
  return (u & 0x80000000u) ? ~u : (u | 0x80000000u);
}
static __device__ __forceinline__ float fdec(unsigned u) {
  u = (u & 0x80000000u) ? (u & 0x7fffffffu) : ~u;
  return __uint_as_float(u);
}

// ---------------- init: hx=gcn_weights, cx=0, has/first=0, keys=0 ----------------
__global__ void k_init(const float* __restrict__ gcn, float* __restrict__ hx,
                       float* __restrict__ cx, int* __restrict__ hasfirst,
                       unsigned* __restrict__ keys) {
  int i = blockIdx.x * blockDim.x + threadIdx.x;
  if (i < LLAYERS * DIM * DIM) { hx[i] = gcn[i]; cx[i] = 0.f; }
  if (i < BGRAPH * DIM) keys[i] = 0u;
  if (i < 16) hasfirst[i] = 0;
}

// ---------------- has[t] histogram ----------------
__global__ void k_hist(const int* __restrict__ et, int* __restrict__ hasfirst) {
  __shared__ int loc[TSTEPS];
  if (threadIdx.x < TSTEPS) loc[threadIdx.x] = 0;
  __syncthreads();
  for (int e = blockIdx.x * blockDim.x + threadIdx.x; e < E_EDGES;
       e += gridDim.x * blockDim.x) {
    int t = et[e];
    if (t >= 0 && t < TSTEPS) loc[t] = 1;
  }
  __syncthreads();
  if (threadIdx.x < TSTEPS && loc[threadIdx.x]) atomicOr(&hasfirst[threadIdx.x], 1);
}

// first[t] = OR of has[0..t-1]; first stored at hasfirst[8+t]
__global__ void k_first(int* __restrict__ hasfirst) {
  if (blockIdx.x == 0 && threadIdx.x == 0) {
    int f = 0;
    for (int t = 0; t < TSTEPS; ++t) { hasfirst[8 + t] = f; f |= hasfirst[t]; }
  }
}

// ---------------- zero float4 region ----------------
__global__ void k_zero(float4* __restrict__ p, long n4) {
  long i = (long)blockIdx.x * blockDim.x + threadIdx.x;
  if (i < n4) p[i] = make_float4(0.f, 0.f, 0.f, 0.f);
}

// ---------------- touched flags for time-t edges ----------------
__global__ void k_touch(const int* __restrict__ src, const int* __restrict__ dst,
                        const int* __restrict__ et, int* __restrict__ touched, int t) {
  int e = blockIdx.x * blockDim.x + threadIdx.x;
  if (e < E_EDGES && et[e] == t) {
    touched[src[e]] = 1;
    touched[dst[e]] = 1;
  }
}

// ---------------- LSTM part 1: g0 = x@Wih^T + b, g1 = x@(Wih+Whh)^T + b ----------------
// layout of g: [layer][c(=4D)][r(=D)] so that part-2 reads are coalesced in r
__global__ void k_lstm_g(const float* __restrict__ hx, const float* __restrict__ Wih,
                         const float* __restrict__ Whh, const float* __restrict__ bih,
                         const float* __restrict__ bhh, float* __restrict__ g0,
                         float* __restrict__ g1) {
  int i = blockIdx.x >> 9;          // layer
  int c = blockIdx.x & 511;         // gate column 0..511
  int r = threadIdx.x;              // 0..127
  __shared__ float wi[DIM], wh[DIM];
  wi[r] = Wih[((long)i * 4 * DIM + c) * DIM + r];
  wh[r] = Whh[((long)i * 4 * DIM + c) * DIM + r];
  __syncthreads();
  const float* x = hx + ((long)i * DIM + r) * DIM;
  float a = 0.f, b = 0.f;
#pragma unroll 8
  for (int k = 0; k < DIM; ++k) {
    a = fmaf(x[k], wi[k], a);
    b = fmaf(x[k], wh[k], b);
  }
  float base = bih[i * 4 * DIM + c] + bhh[i * 4 * DIM + c];
  long o = ((long)i * 4 * DIM + c) * DIM + r;
  g0[o] = a + base;
  g1[o] = a + b + base;
}

// ---------------- LSTM part 2: gate nonlinearities + select, update hx/cx ----------------
__global__ void k_lstm_upd(float* __restrict__ hx, float* __restrict__ cx,
                           const float* __restrict__ g0, const float* __restrict__ g1,
                           const int* __restrict__ hasfirst, int t) {
  int idx = blockIdx.x * blockDim.x + threadIdx.x;
  if (idx >= LLAYERS * DIM * DIM) return;
  int i = idx >> 14;
  int rem = idx & 16383;
  int r = rem >> 7, j = rem & 127;
  long gb = (long)i * 4 * DIM * DIM;
  float gi0 = g0[gb + (0 * DIM + j) * DIM + r];
  float gg0 = g0[gb + (2 * DIM + j) * DIM + r];
  float go0 = g0[gb + (3 * DIM + j) * DIM + r];
  float gi1 = g1[gb + (0 * DIM + j) * DIM + r];
  float gf1 = g1[gb + (1 * DIM + j) * DIM + r];
  float gg1 = g1[gb + (2 * DIM + j) * DIM + r];
  float go1 = g1[gb + (3 * DIM + j) * DIM + r];
  float c_zero = sigm(gi0) * tanhf(gg0);
  float h_zero = sigm(go0) * tanhf(c_zero);
  float c0v = cx[idx];
  float c_st = sigm(gf1) * c0v + sigm(gi1) * tanhf(gg1);
  float h_st = sigm(go1) * tanhf(c_st);
  int first = hasfirst[8 + t];
  int has = hasfirst[t];
  float hold = hx[idx];
  float hi_v = first ? h_st : h_zero;
  float ci_v = first ? c0v : c_zero;
  hx[idx] = has ? hi_v : hold;
  cx[idx] = has ? ci_v : c0v;
}

// ---------------- edge scatter: S[dst] += w * H[src] for time-t edges ----------------
__global__ void k_scatter(const int* __restrict__ src, const int* __restrict__ dst,
                          const int* __restrict__ et, const float* __restrict__ ew,
                          const float* __restrict__ H, float* __restrict__ S, int t) {
  int idx = blockIdx.x * blockDim.x + threadIdx.x;
  int e = idx >> 5;
  if (e >= E_EDGES) return;
  if (et[e] != t) return;
  int d = (idx & 31) << 2;
  float w = ew[e];
  const float4 hv = *reinterpret_cast<const float4*>(H + (long)src[e] * DIM + d);
  float* o = S + (long)dst[e] * DIM + d;
  atomicAdd(o + 0, hv.x * w);
  atomicAdd(o + 1, hv.y * w);
  atomicAdd(o + 2, hv.z * w);
  atomicAdd(o + 3, hv.w * w);
}

// ---------------- GEMM: C[n][c] = act(sum_k A[row(n)][k] * W[k][c] (+bias)) ----------------
// 64 rows x 128 cols per block, 256 threads, 4x8 register tile per thread
template <int K, bool GATHER, bool RELU, bool BIAS>
__global__ __launch_bounds__(256) void k_gemm(const float* __restrict__ A,
                                              const int* __restrict__ rowids,
                                              const float* __restrict__ W,
                                              const float* __restrict__ bias,
                                              float* __restrict__ C, int N) {
  __shared__ float As[64][17];
  __shared__ float Ws[16][128];
  __shared__ int rid[64];
  const int tid = threadIdx.x;
  const int n0 = blockIdx.x * 64;
  if (GATHER) {
    if (tid < 64) {
      int n = n0 + tid;
      rid[tid] = (n < N) ? rowids[n] * K : 0;
    }
    __syncthreads();
  }
  const int ty = tid >> 4, tx = tid & 15;
  float acc[4][8] = {};
  for (int kk = 0; kk < K; kk += 16) {
#pragma unroll
    for (int p = 0; p < 4; ++p) {
      int idx = p * 256 + tid;
      int r = idx >> 4, k = idx & 15;
      int n = n0 + r;
      float v = 0.f;
      if (n < N) {
        long base = GATHER ? (long)rid[r] : (long)n * K;
        v = A[base + kk + k];
      }
      As[r][k] = v;
    }
#pragma unroll
    for (int p = 0; p < 2; ++p) {
      int idx = p * 256 + tid;
      int k = idx >> 5, c4 = (idx & 31) << 2;
      *reinterpret_cast<float4*>(&Ws[k][c4]) =
          *reinterpret_cast<const float4*>(&W[(long)(kk + k) * DIM + c4]);
    }
    __syncthreads();
#pragma unroll
    for (int k = 0; k < 16; ++k) {
      float a[4];
#pragma unroll
      for (int i2 = 0; i2 < 4; ++i2) a[i2] = As[ty * 4 + i2][k];
      float w[8];
#pragma unroll
      for (int j = 0; j < 8; ++j) w[j] = Ws[k][tx * 4 + (j & 3) + ((j >> 2) << 6)];
#pragma unroll
      for (int i2 = 0; i2 < 4; ++i2)
#pragma unroll
        for (int j = 0; j < 8; ++j) acc[i2][j] = fmaf(a[i2], w[j], acc[i2][j]);
    }
    __syncthreads();
  }
#pragma unroll
  for (int i2 = 0; i2 < 4; ++i2) {
    int n = n0 + ty * 4 + i2;
    if (n >= N) continue;
#pragma unroll
    for (int g = 0; g < 2; ++g) {
      float4 v;
      float* vp = &v.x;
#pragma unroll
      for (int q = 0; q < 4; ++q) {
        int c = tx * 4 + q + (g << 6);
        float x = acc[i2][g * 4 + q];
        if (BIAS) x += bias[c];
        if (RELU) x = fmaxf(x, 0.f);
        vp[q] = x;
      }
      *reinterpret_cast<float4*>(&C[(long)n * DIM + tx * 4 + (g << 6)]) = v;
    }
  }
}

// ---------------- write back touched rows: h[n] = ht[n] ----------------
__global__ void k_writeback(float* __restrict__ h, const float* __restrict__ ht,
                            const int* __restrict__ touched) {
  int idx = blockIdx.x * blockDim.x + threadIdx.x;
  int n = idx >> 5;
  if (n >= N_NODES) return;
  if (!touched[n]) return;
  int d = (idx & 31) << 2;
  *reinterpret_cast<float4*>(h + (long)n * DIM + d) =
      *reinterpret_cast<const float4*>(ht + (long)n * DIM + d);
}

// ---------------- segment max (graph_id sorted) ----------------
__global__ void k_segmax(const float* __restrict__ h, const int* __restrict__ gid,
                         unsigned* __restrict__ keys) {
  int d = threadIdx.x;  // 0..127
  int n0 = blockIdx.x * 64;
  int end = min(n0 + 64, N_NODES);
  if (n0 >= N_NODES) return;
  int curg = gid[n0];
  float m = -INFINITY;
  for (int n = n0; n < end; ++n) {
    int g = gid[n];
    if (g != curg) {
      atomicMax(&keys[(long)curg * DIM + d], fenc(m));
      curg = g;
      m = -INFINITY;
    }
    m = fmaxf(m, h[(long)n * DIM + d]);
  }
  atomicMax(&keys[(long)curg * DIM + d], fenc(m));
}

// ---------------- final: logits, probs, BCE loss ----------------
__global__ void k_final(const unsigned* __restrict__ keys, const float* __restrict__ outW,
                        const float* __restrict__ outB, const float* __restrict__ y,
                        float* __restrict__ out) {
  __shared__ float lt[BGRAPH];
  int tid = threadIdx.x;  // 64 threads: 4 per graph
  int b = tid >> 2, l4 = tid & 3;
  float s = 0.f;
  for (int d = l4; d < DIM; d += 4) {
    float v = fdec(keys[(long)b * DIM + d]);
    if (!isfinite(v)) v = 0.f;
    s += v * outW[d];
  }
  s += __shfl_down(s, 1);
  s += __shfl_down(s, 2);
  if (l4 == 0) {
    float l = s + outB[0];
    out[1 + b] = 1.f / (1.f + expf(-l));
    lt[b] = fmaxf(l, 0.f) - l * y[b] + log1pf(expf(-fabsf(l)));
  }
  __syncthreads();
  if (tid == 0) {
    float acc = 0.f;
    for (int i = 0; i < BGRAPH; ++i) acc += lt[i];
    out[0] = acc / (float)BGRAPH;
  }
}

extern "C" void kernel_launch(void* const* d_in, const int* in_sizes, int n_in,
                              void* d_out, int out_size, void* d_ws, size_t ws_size,
                              hipStream_t stream) {
  const int* word_ids = (const int*)d_in[0];
  const int* src = (const int*)d_in[1];
  const int* dst = (const int*)d_in[2];
  const int* et = (const int*)d_in[3];
  const float* ew = (const float*)d_in[4];
  const int* gid = (const int*)d_in[5];
  const float* y = (const float*)d_in[6];
  const float* wemb = (const float*)d_in[7];
  const float* adW = (const float*)d_in[8];
  const float* adb = (const float*)d_in[9];
  const float* gcn = (const float*)d_in[10];
  const float* Wih = (const float*)d_in[11];
  const float* Whh = (const float*)d_in[12];
  const float* bih = (const float*)d_in[13];
  const float* bhh = (const float*)d_in[14];
  const float* outW = (const float*)d_in[15];
  const float* outB = (const float*)d_in[16];
  float* out = (float*)d_out;

  char* ws = (char*)d_ws;
  const long ND = (long)N_NODES * DIM;  // 7,680,000 floats
  float* h = (float*)ws;        ws += ND * 4;
  float* tA = (float*)ws;       ws += ND * 4;
  float* S = (float*)ws;        ws += ND * 4;
  int* touched = (int*)ws;      ws += (long)N_NODES * 4;  // 240000 B (16B multiple)
  float* hx = (float*)ws;       ws += LLAYERS * DIM * DIM * 4;
  float* cx = (float*)ws;       ws += LLAYERS * DIM * DIM * 4;
  float* g0 = (float*)ws;       ws += LLAYERS * 4 * DIM * DIM * 4;
  float* g1 = (float*)ws;       ws += LLAYERS * 4 * DIM * DIM * 4;
  int* hasfirst = (int*)ws;     ws += 16 * 4;
  unsigned* keys = (unsigned*)ws;

  const long n4_S = ND / 4;                            // S only
  const long n4_S_touch = (ND * 4 + N_NODES * 4) / 16; // S + touched (contiguous)
  const int gemm_blocks = (N_NODES + 63) / 64;

  k_init<<<128, 256, 0, stream>>>(gcn, hx, cx, hasfirst, keys);
  k_hist<<<256, 256, 0, stream>>>(et, hasfirst);
  k_first<<<1, 64, 0, stream>>>(hasfirst);

  // h0 = word_embeds[word_ids] @ adapt_W + adapt_b
  k_gemm<NINPK, true, false, true><<<gemm_blocks, 256, 0, stream>>>(
      wemb, word_ids, adW, adb, h, N_NODES);

  for (int t = 0; t < TSTEPS; ++t) {
    // zero S + touched
    k_zero<<<(int)((n4_S_touch + 255) / 256), 256, 0, stream>>>((float4*)S, n4_S_touch);
    k_touch<<<(E_EDGES + 255) / 256, 256, 0, stream>>>(src, dst, et, touched, t);
    // LSTM weight evolution
    k_lstm_g<<<LLAYERS * 512, 128, 0, stream>>>(hx, Wih, Whh, bih, bhh, g0, g1);
    k_lstm_upd<<<128, 256, 0, stream>>>(hx, cx, g0, g1, hasfirst, t);
    // GCN layer 0: S = scatter(h), tA = relu(S @ hx[0])
    k_scatter<<<E_EDGES * 32 / 256, 256, 0, stream>>>(src, dst, et, ew, h, S, t);
    k_gemm<DIM, false, true, false><<<gemm_blocks, 256, 0, stream>>>(
        S, nullptr, hx, nullptr, tA, N_NODES);
    // GCN layer 1: S = scatter(tA), tA = relu(S @ hx[1])
    k_zero<<<(int)((n4_S + 255) / 256), 256, 0, stream>>>((float4*)S, n4_S);
    k_scatter<<<E_EDGES * 32 / 256, 256, 0, stream>>>(src, dst, et, ew, tA, S, t);
    k_gemm<DIM, false, true, false><<<gemm_blocks, 256, 0, stream>>>(
        S, nullptr, hx + DIM * DIM, nullptr, tA, N_NODES);
    // write back touched rows
    k_writeback<<<N_NODES * 32 / 256, 256, 0, stream>>>(h, tA, touched);
  }

  k_segmax<<<(N_NODES + 63) / 64, 128, 0, stream>>>(h, gid, keys);
  k_final<<<1, 64, 0, stream>>>(keys, outW, outB, y, out);
}